// Round 6
// baseline (459.989 us; speedup 1.0000x reference)
//
#include <hip/hip_runtime.h>

#define V 32
#define B 128
#define P 256
#define J 75
#define NF 32
#define S2 25

// ---------------------------------------------------------------------------
// Kernel 1: transform + SLayer with mask compaction. (round-3 verified)
// ---------------------------------------------------------------------------
__global__ __launch_bounds__(256) void slayer_kernel(
    const float* __restrict__ births,
    const float* __restrict__ lifetimes,
    const int* __restrict__ mask,
    const float* __restrict__ centers,
    const float* __restrict__ sharpness,
    float* __restrict__ z)                     // [V*B, J]
{
    const int vb = blockIdx.x;                 // v*B + b
    const int v  = vb >> 7;                    // / 128
    const int tid = threadIdx.x;
    const int lane = tid & 63;

    __shared__ float4 pts[P];
    __shared__ int cnt;
    __shared__ float part[2][J];

    if (tid == 0) cnt = 0;
    __syncthreads();

    const float inv = 0.70710678118654752f;
    {
        const int gi = vb * P + tid;
        float b0 = births[gi];
        float l0 = lifetimes[gi];
        int   m  = mask[gi];
        float d  = b0 + l0 + 0.01f;
        float x  = (b0 + d) * inv;
        float y  = (d - b0) * inv;
        if (y <= 0.1f) y = __logf(y * 10.0f) * 0.1f + 0.1f;

        bool keep = (m != 0);
        unsigned long long bal = __ballot(keep);
        unsigned long long lt  = (1ull << lane) - 1ull;
        int prefix = __popcll(bal & lt);
        int total  = __popcll(bal);
        int base = 0;
        if (lane == 0) base = atomicAdd(&cnt, total);
        base = __shfl(base, 0, 64);
        if (keep) pts[base + prefix] = make_float4(x, y, x * x, y * y);
    }
    __syncthreads();

    const int n = cnt;
    float acc = 0.f;
    if (tid < 3 * J) {
        const int pid = tid / J;               // 0,1,2
        const int j   = tid - pid * J;
        const int cj  = (v * J + j) * 2;
        float cx = centers[cj + 0];
        float cy = centers[cj + 1];
        float sx = sharpness[cj + 0];
        float sy = sharpness[cj + 1];
        float s2x = sx * sx, s2y = sy * sy;
        float k0 = -s2x;
        float k1 = -s2y;
        float k2 = 2.0f * s2x * cx;
        float k3 = 2.0f * s2y * cy;
        float kc = -(s2x * cx * cx + s2y * cy * cy);
        const int p0 = (n * pid) / 3;
        const int p1 = (n * (pid + 1)) / 3;
        #pragma unroll 4
        for (int p = p0; p < p1; ++p) {
            float4 a = pts[p];
            float d = fmaf(k0, a.z, kc);
            d = fmaf(k1, a.w, d);
            d = fmaf(k2, a.x, d);
            d = fmaf(k3, a.y, d);
            acc += __expf(d);
        }
        if (pid > 0) part[pid - 1][j] = acc;
    }
    __syncthreads();

    if (tid < J)
        z[vb * J + tid] = acc + part[0][tid] + part[1][tid];
}

// ---------------------------------------------------------------------------
// Kernel 2 (merged, FENCE-FREE): stage12 + BN1 + l2 + ReLU -> xT.
// One block per v, 1024 threads.  The whole batch lives in this block, so
// BN over the batch axis is a plain LDS reduction — __syncthreads only,
// no atomics, no __threadfence, no cross-block protocol.
// LDS: hs 38.4K + us 12.8K + weights ~11.6K + red ~3.4K = ~66 KB (1 blk/CU).
// ---------------------------------------------------------------------------
__global__ __launch_bounds__(1024) void stage2_kernel(
    const float* __restrict__ z,               // [V*B, J]
    const float* __restrict__ w1,              // [V, NF, 3]
    const float* __restrict__ w2,              // [V, 8, NF]
    const float* __restrict__ l1_w,            // [V, S2, J]
    const float* __restrict__ l1_b,            // [V, S2]
    const float* __restrict__ bn1_g,
    const float* __restrict__ bn1_b,
    const float* __restrict__ l2_w,            // [V, S2, S2]
    const float* __restrict__ l2_b,            // [V, S2]
    float* __restrict__ xT)                    // [V*S2, B]
{
    const int v   = blockIdx.x;
    const int tid = threadIdx.x;
    const int vm  = (v + V - 1) & (V - 1);
    const int vp  = (v + 1) & (V - 1);

    __shared__ float w1s[NF * 3];              // 96
    __shared__ float w2s[8 * NF];              // 256
    __shared__ float l1ws[S2 * J];             // 1875
    __shared__ float l1bs[S2];
    __shared__ float wl2[S2 * S2];             // 625
    __shared__ float l2bs[S2];
    __shared__ float hs[B * J];                // 9600 floats = 38.4 KB
    __shared__ float us[B * S2];               // 3200 floats = 12.8 KB
    __shared__ float sred[32 * S2], ssred[32 * S2];
    __shared__ float sc[S2], sh[S2];

    // ---- stage all weights once ----
    for (int i = tid; i < NF * 3;  i += 1024) w1s[i]  = w1[v * NF * 3 + i];
    for (int i = tid; i < 8 * NF;  i += 1024) w2s[i]  = w2[v * 8 * NF + i];
    for (int i = tid; i < S2 * J;  i += 1024) l1ws[i] = l1_w[v * S2 * J + i];
    for (int i = tid; i < S2 * S2; i += 1024) wl2[i]  = l2_w[v * S2 * S2 + i];
    if (tid < S2) { l1bs[tid] = l1_b[v * S2 + tid]; l2bs[tid] = l2_b[v * S2 + tid]; }
    __syncthreads();

    // ---- conv1 + conv2 + max8: 9600 tasks (b*J + j == t, coalesced z) ----
    for (int t = tid; t < B * J; t += 1024) {
        float a0 = z[vm * (B * J) + t];
        float a1 = z[v  * (B * J) + t];
        float a2 = z[vp * (B * J) + t];
        float hf[NF];
        #pragma unroll
        for (int f = 0; f < NF; ++f)
            hf[f] = w1s[f * 3 + 0] * a0 + w1s[f * 3 + 1] * a1 + w1s[f * 3 + 2] * a2;
        float hm = -3.4e38f;
        #pragma unroll
        for (int g = 0; g < 8; ++g) {
            float s = 0.f;
            #pragma unroll
            for (int f = 0; f < NF; ++f) s += w2s[g * NF + f] * hf[f];
            hm = fmaxf(hm, s);
        }
        hs[t] = hm;
    }
    __syncthreads();

    // ---- l1: 3200 tasks, t = o*128 + b (wave-uniform o -> l1ws broadcast) --
    for (int t = tid; t < S2 * B; t += 1024) {
        int o = t >> 7;
        int b = t & 127;
        float acc = l1bs[o];
        const float* hrow = hs + b * J;
        const float* wrow = l1ws + o * J;
        #pragma unroll 5
        for (int j = 0; j < J; ++j) acc += hrow[j] * wrow[j];
        us[b * S2 + o] = acc;
    }
    __syncthreads();

    // ---- BN stats over batch: 32 chunks x 25 outputs -----------------------
    if (tid < 32 * S2) {
        int c = tid / S2;
        int o = tid - c * S2;
        float s = 0.f, ss = 0.f;
        #pragma unroll
        for (int b = c * 4; b < c * 4 + 4; ++b) {
            float x = us[b * S2 + o];
            s += x; ss += x * x;
        }
        sred[tid] = s; ssred[tid] = ss;
    }
    __syncthreads();

    if (tid < S2) {
        float s = 0.f, ss = 0.f;
        #pragma unroll
        for (int c = 0; c < 32; ++c) { s += sred[c * S2 + tid]; ss += ssred[c * S2 + tid]; }
        float mean = s * (1.f / B);
        float var  = ss * (1.f / B) - mean * mean;
        float istd = rsqrtf(var + 1e-5f);
        float g  = bn1_g[v * S2 + tid];
        float be = bn1_b[v * S2 + tid];
        sc[tid] = g * istd;
        sh[tid] = be - mean * g * istd;
    }
    __syncthreads();

    // ---- normalize in place ------------------------------------------------
    for (int i = tid; i < B * S2; i += 1024) {
        int o = i % S2;
        us[i] = us[i] * sc[o] + sh[o];
    }
    __syncthreads();

    // ---- l2 + ReLU -> xT (t = p*128 + b: coalesced xT writes) --------------
    for (int t = tid; t < S2 * B; t += 1024) {
        int p = t >> 7;
        int b = t & 127;
        float acc = l2bs[p];
        const float* urow = us + b * S2;
        const float* wrow = wl2 + p * S2;
        #pragma unroll
        for (int o = 0; o < S2; ++o) acc += urow[o] * wrow[o];
        acc = fmaxf(acc, 0.f);
        xT[(v * S2 + p) * B + b] = acc;
    }
}

// ---------------------------------------------------------------------------
// Kernel 3: fc1 + BN over batch.  (round-3 verified)
// ---------------------------------------------------------------------------
__global__ __launch_bounds__(256) void fc1_bn2_kernel(
    const float* __restrict__ xT,              // [800, B]
    const float* __restrict__ fc1_w,           // [500, 800]
    const float* __restrict__ fc1_b,           // [500]
    const float* __restrict__ bn2_g,
    const float* __restrict__ bn2_b,
    float* __restrict__ y1n)                   // [500, B]
{
    const int n  = blockIdx.x;                 // neuron
    const int tid = threadIdx.x;
    const int kk = tid >> 7;                   // 0/1: K half
    const int b  = tid & 127;
    const int K  = V * S2;                     // 800

    __shared__ float wsm[V * S2];
    __shared__ float pr[B];
    __shared__ float red[2][2];

    for (int i = tid; i < K; i += 256) wsm[i] = fc1_w[n * K + i];
    __syncthreads();

    float acc = 0.f;
    const float* xp = xT + kk * 400 * B + b;
    const float* wp = wsm + kk * 400;
    for (int k = 0; k < 400; ++k) acc += xp[k * B] * wp[k];

    if (kk == 1) pr[b] = acc;
    __syncthreads();

    float t = 0.f;
    if (kk == 0) {
        t = acc + pr[b] + fc1_b[n];
        const int wave = tid >> 6;             // 0/1
        const int lane = tid & 63;
        float s = t, ss = t * t;
        #pragma unroll
        for (int off = 32; off > 0; off >>= 1) {
            s  += __shfl_down(s,  off, 64);
            ss += __shfl_down(ss, off, 64);
        }
        if (lane == 0) { red[wave][0] = s; red[wave][1] = ss; }
    }
    __syncthreads();

    if (kk == 0) {
        float s  = red[0][0] + red[1][0];
        float ss = red[0][1] + red[1][1];
        float mean = s * (1.f / B);
        float var  = ss * (1.f / B) - mean * mean;
        float istd = rsqrtf(var + 1e-5f);
        float g   = bn2_g[n];
        float be  = bn2_b[n];
        float scl = g * istd;
        y1n[n * B + b] = t * scl + (be - mean * scl);
    }
}

// ---------------------------------------------------------------------------
// Kernel 4: fc2.  (round-3 verified)
// ---------------------------------------------------------------------------
__global__ __launch_bounds__(256) void fc2_kernel(
    const float* __restrict__ y1n,             // [500, B]
    const float* __restrict__ fc2_w,           // [200, 500]
    const float* __restrict__ fc2_b,           // [200]
    float* __restrict__ out)                   // [B, 200]
{
    const int n2 = blockIdx.x;
    const int tid = threadIdx.x;
    const int kk = tid >> 7;
    const int b  = tid & 127;

    __shared__ float wsm[500];
    __shared__ float pr[B];
    for (int i = tid; i < 500; i += 256) wsm[i] = fc2_w[n2 * 500 + i];
    __syncthreads();

    float acc = 0.f;
    const float* yp = y1n + kk * 250 * B + b;
    const float* wp = wsm + kk * 250;
    for (int k = 0; k < 250; ++k) acc += yp[k * B] * wp[k];

    if (kk == 1) pr[b] = acc;
    __syncthreads();

    if (kk == 0)
        out[b * 200 + n2] = acc + pr[b] + fc2_b[n2];
}

// ---------------------------------------------------------------------------
extern "C" void kernel_launch(void* const* d_in, const int* in_sizes, int n_in,
                              void* d_out, int out_size, void* d_ws, size_t ws_size,
                              hipStream_t stream) {
    const float* births    = (const float*)d_in[0];
    const float* lifetimes = (const float*)d_in[1];
    const int*   mask      = (const int*)d_in[2];
    const float* centers   = (const float*)d_in[3];
    const float* sharpness = (const float*)d_in[4];
    const float* w1        = (const float*)d_in[5];
    const float* w2        = (const float*)d_in[6];
    const float* l1_w      = (const float*)d_in[7];
    const float* l1_b      = (const float*)d_in[8];
    const float* bn1_g     = (const float*)d_in[9];
    const float* bn1_b     = (const float*)d_in[10];
    const float* l2_w      = (const float*)d_in[11];
    const float* l2_b      = (const float*)d_in[12];
    const float* fc1_w     = (const float*)d_in[13];
    const float* fc1_b     = (const float*)d_in[14];
    const float* bn2_g     = (const float*)d_in[15];
    const float* bn2_b     = (const float*)d_in[16];
    const float* fc2_w     = (const float*)d_in[17];
    const float* fc2_b     = (const float*)d_in[18];
    float* out = (float*)d_out;

    float* ws    = (float*)d_ws;
    float* z     = ws;                            // V*B*J   = 307200
    float* xT    = ws + 307200;                   // 800*B   = 102400
    float* y1n   = ws + 307200 + 102400;          // 500*B   = 64000

    slayer_kernel <<<V * B, 256, 0, stream>>>(births, lifetimes, mask, centers, sharpness, z);
    stage2_kernel <<<V, 1024, 0, stream>>>(z, w1, w2, l1_w, l1_b, bn1_g, bn1_b,
                                           l2_w, l2_b, xT);
    fc1_bn2_kernel<<<500, 256, 0, stream>>>(xT, fc1_w, fc1_b, bn2_g, bn2_b, y1n);
    fc2_kernel    <<<200, 256, 0, stream>>>(y1n, fc2_w, fc2_b, out);
}

// Round 7
// 147.815 us; speedup vs baseline: 3.1119x; 3.1119x over previous
//
#include <hip/hip_runtime.h>

#define V 32
#define B 128
#define P 256
#define J 75
#define NF 32
#define S2 25

// ---------------------------------------------------------------------------
// Kernel 1: transform + SLayer with mask compaction. (round-3 verified)
// ---------------------------------------------------------------------------
__global__ __launch_bounds__(256) void slayer_kernel(
    const float* __restrict__ births,
    const float* __restrict__ lifetimes,
    const int* __restrict__ mask,
    const float* __restrict__ centers,
    const float* __restrict__ sharpness,
    float* __restrict__ z)                     // [V*B, J]
{
    const int vb = blockIdx.x;                 // v*B + b
    const int v  = vb >> 7;                    // / 128
    const int tid = threadIdx.x;
    const int lane = tid & 63;

    __shared__ float4 pts[P];
    __shared__ int cnt;
    __shared__ float part[2][J];

    if (tid == 0) cnt = 0;
    __syncthreads();

    const float inv = 0.70710678118654752f;
    {
        const int gi = vb * P + tid;
        float b0 = births[gi];
        float l0 = lifetimes[gi];
        int   m  = mask[gi];
        float d  = b0 + l0 + 0.01f;
        float x  = (b0 + d) * inv;
        float y  = (d - b0) * inv;
        if (y <= 0.1f) y = __logf(y * 10.0f) * 0.1f + 0.1f;

        bool keep = (m != 0);
        unsigned long long bal = __ballot(keep);
        unsigned long long lt  = (1ull << lane) - 1ull;
        int prefix = __popcll(bal & lt);
        int total  = __popcll(bal);
        int base = 0;
        if (lane == 0) base = atomicAdd(&cnt, total);
        base = __shfl(base, 0, 64);
        if (keep) pts[base + prefix] = make_float4(x, y, x * x, y * y);
    }
    __syncthreads();

    const int n = cnt;
    float acc = 0.f;
    if (tid < 3 * J) {
        const int pid = tid / J;               // 0,1,2
        const int j   = tid - pid * J;
        const int cj  = (v * J + j) * 2;
        float cx = centers[cj + 0];
        float cy = centers[cj + 1];
        float sx = sharpness[cj + 0];
        float sy = sharpness[cj + 1];
        float s2x = sx * sx, s2y = sy * sy;
        float k0 = -s2x;
        float k1 = -s2y;
        float k2 = 2.0f * s2x * cx;
        float k3 = 2.0f * s2y * cy;
        float kc = -(s2x * cx * cx + s2y * cy * cy);
        const int p0 = (n * pid) / 3;
        const int p1 = (n * (pid + 1)) / 3;
        #pragma unroll 4
        for (int p = p0; p < p1; ++p) {
            float4 a = pts[p];
            float d = fmaf(k0, a.z, kc);
            d = fmaf(k1, a.w, d);
            d = fmaf(k2, a.x, d);
            d = fmaf(k3, a.y, d);
            acc += __expf(d);
        }
        if (pid > 0) part[pid - 1][j] = acc;
    }
    __syncthreads();

    if (tid < J)
        z[vb * J + tid] = acc + part[0][tid] + part[1][tid];
}

// ---------------------------------------------------------------------------
// Kernel 2 (merged, FENCE-FREE): stage12 + BN1 + l2 + ReLU -> xT.
// One block per v, 1024 threads.  BN over batch is a plain LDS reduction.
//
// KEY FIX vs round 6: conv1 and conv2 have NO nonlinearity between them,
// so w2[8,NF] @ w1[NF,3] composes into wcomb[8][3] computed once per block.
// Conv task = 24 FMA + 8 max, no per-thread hf[32] array -> no scratch
// spill under the 64-VGPR cap of __launch_bounds__(1024).
// ---------------------------------------------------------------------------
__global__ __launch_bounds__(1024) void stage2_kernel(
    const float* __restrict__ z,               // [V*B, J]
    const float* __restrict__ w1,              // [V, NF, 3]
    const float* __restrict__ w2,              // [V, 8, NF]
    const float* __restrict__ l1_w,            // [V, S2, J]
    const float* __restrict__ l1_b,            // [V, S2]
    const float* __restrict__ bn1_g,
    const float* __restrict__ bn1_b,
    const float* __restrict__ l2_w,            // [V, S2, S2]
    const float* __restrict__ l2_b,            // [V, S2]
    float* __restrict__ xT)                    // [V*S2, B]
{
    const int v   = blockIdx.x;
    const int tid = threadIdx.x;
    const int vm  = (v + V - 1) & (V - 1);
    const int vp  = (v + 1) & (V - 1);

    __shared__ float wcomb[8][3];              // composed conv weights
    __shared__ float l1ws[S2 * J];             // 1875
    __shared__ float l1bs[S2];
    __shared__ float wl2[S2 * S2];             // 625
    __shared__ float l2bs[S2];
    __shared__ float hs[B * J];                // 9600 floats = 38.4 KB
    __shared__ float us[B * S2];               // 3200 floats = 12.8 KB
    __shared__ float sred[32 * S2], ssred[32 * S2];
    __shared__ float sc[S2], sh[S2];

    // ---- compose conv weights: wcomb[g][c] = sum_f w2[g,f] * w1[f,c] ------
    if (tid < 24) {
        int g = tid / 3, c = tid - g * 3;
        const float* w2r = w2 + v * 8 * NF + g * NF;
        const float* w1c = w1 + v * NF * 3 + c;
        float s = 0.f;
        #pragma unroll
        for (int f = 0; f < NF; ++f) s += w2r[f] * w1c[f * 3];
        wcomb[g][c] = s;
    }
    for (int i = tid; i < S2 * J;  i += 1024) l1ws[i] = l1_w[v * S2 * J + i];
    for (int i = tid; i < S2 * S2; i += 1024) wl2[i]  = l2_w[v * S2 * S2 + i];
    if (tid < S2) { l1bs[tid] = l1_b[v * S2 + tid]; l2bs[tid] = l2_b[v * S2 + tid]; }
    __syncthreads();

    // ---- composed conv + max8: 9600 tasks (coalesced z reads) --------------
    for (int t = tid; t < B * J; t += 1024) {
        float a0 = z[vm * (B * J) + t];
        float a1 = z[v  * (B * J) + t];
        float a2 = z[vp * (B * J) + t];
        float hm = -3.4e38f;
        #pragma unroll
        for (int g = 0; g < 8; ++g) {
            float s = wcomb[g][0] * a0 + wcomb[g][1] * a1 + wcomb[g][2] * a2;
            hm = fmaxf(hm, s);
        }
        hs[t] = hm;
    }
    __syncthreads();

    // ---- l1: 3200 tasks, t = o*128 + b (wave-uniform o -> l1ws broadcast) --
    for (int t = tid; t < S2 * B; t += 1024) {
        int o = t >> 7;
        int b = t & 127;
        float acc = l1bs[o];
        const float* hrow = hs + b * J;
        const float* wrow = l1ws + o * J;
        #pragma unroll 5
        for (int j = 0; j < J; ++j) acc += hrow[j] * wrow[j];
        us[b * S2 + o] = acc;
    }
    __syncthreads();

    // ---- BN stats over batch: 32 chunks x 25 outputs -----------------------
    if (tid < 32 * S2) {
        int c = tid / S2;
        int o = tid - c * S2;
        float s = 0.f, ss = 0.f;
        #pragma unroll
        for (int b = c * 4; b < c * 4 + 4; ++b) {
            float x = us[b * S2 + o];
            s += x; ss += x * x;
        }
        sred[tid] = s; ssred[tid] = ss;
    }
    __syncthreads();

    if (tid < S2) {
        float s = 0.f, ss = 0.f;
        #pragma unroll
        for (int c = 0; c < 32; ++c) { s += sred[c * S2 + tid]; ss += ssred[c * S2 + tid]; }
        float mean = s * (1.f / B);
        float var  = ss * (1.f / B) - mean * mean;
        float istd = rsqrtf(var + 1e-5f);
        float g  = bn1_g[v * S2 + tid];
        float be = bn1_b[v * S2 + tid];
        sc[tid] = g * istd;
        sh[tid] = be - mean * g * istd;
    }
    __syncthreads();

    // ---- normalize in place ------------------------------------------------
    for (int i = tid; i < B * S2; i += 1024) {
        int o = i % S2;
        us[i] = us[i] * sc[o] + sh[o];
    }
    __syncthreads();

    // ---- l2 + ReLU -> xT (t = p*128 + b: coalesced xT writes) --------------
    for (int t = tid; t < S2 * B; t += 1024) {
        int p = t >> 7;
        int b = t & 127;
        float acc = l2bs[p];
        const float* urow = us + b * S2;
        const float* wrow = wl2 + p * S2;
        #pragma unroll
        for (int o = 0; o < S2; ++o) acc += urow[o] * wrow[o];
        acc = fmaxf(acc, 0.f);
        xT[(v * S2 + p) * B + b] = acc;
    }
}

// ---------------------------------------------------------------------------
// Kernel 3: fc1 + BN over batch.  (round-3 verified)
// ---------------------------------------------------------------------------
__global__ __launch_bounds__(256) void fc1_bn2_kernel(
    const float* __restrict__ xT,              // [800, B]
    const float* __restrict__ fc1_w,           // [500, 800]
    const float* __restrict__ fc1_b,           // [500]
    const float* __restrict__ bn2_g,
    const float* __restrict__ bn2_b,
    float* __restrict__ y1n)                   // [500, B]
{
    const int n  = blockIdx.x;                 // neuron
    const int tid = threadIdx.x;
    const int kk = tid >> 7;                   // 0/1: K half
    const int b  = tid & 127;
    const int K  = V * S2;                     // 800

    __shared__ float wsm[V * S2];
    __shared__ float pr[B];
    __shared__ float red[2][2];

    for (int i = tid; i < K; i += 256) wsm[i] = fc1_w[n * K + i];
    __syncthreads();

    float acc = 0.f;
    const float* xp = xT + kk * 400 * B + b;
    const float* wp = wsm + kk * 400;
    for (int k = 0; k < 400; ++k) acc += xp[k * B] * wp[k];

    if (kk == 1) pr[b] = acc;
    __syncthreads();

    float t = 0.f;
    if (kk == 0) {
        t = acc + pr[b] + fc1_b[n];
        const int wave = tid >> 6;             // 0/1
        const int lane = tid & 63;
        float s = t, ss = t * t;
        #pragma unroll
        for (int off = 32; off > 0; off >>= 1) {
            s  += __shfl_down(s,  off, 64);
            ss += __shfl_down(ss, off, 64);
        }
        if (lane == 0) { red[wave][0] = s; red[wave][1] = ss; }
    }
    __syncthreads();

    if (kk == 0) {
        float s  = red[0][0] + red[1][0];
        float ss = red[0][1] + red[1][1];
        float mean = s * (1.f / B);
        float var  = ss * (1.f / B) - mean * mean;
        float istd = rsqrtf(var + 1e-5f);
        float g   = bn2_g[n];
        float be  = bn2_b[n];
        float scl = g * istd;
        y1n[n * B + b] = t * scl + (be - mean * scl);
    }
}

// ---------------------------------------------------------------------------
// Kernel 4: fc2.  (round-3 verified)
// ---------------------------------------------------------------------------
__global__ __launch_bounds__(256) void fc2_kernel(
    const float* __restrict__ y1n,             // [500, B]
    const float* __restrict__ fc2_w,           // [200, 500]
    const float* __restrict__ fc2_b,           // [200]
    float* __restrict__ out)                   // [B, 200]
{
    const int n2 = blockIdx.x;
    const int tid = threadIdx.x;
    const int kk = tid >> 7;
    const int b  = tid & 127;

    __shared__ float wsm[500];
    __shared__ float pr[B];
    for (int i = tid; i < 500; i += 256) wsm[i] = fc2_w[n2 * 500 + i];
    __syncthreads();

    float acc = 0.f;
    const float* yp = y1n + kk * 250 * B + b;
    const float* wp = wsm + kk * 250;
    for (int k = 0; k < 250; ++k) acc += yp[k * B] * wp[k];

    if (kk == 1) pr[b] = acc;
    __syncthreads();

    if (kk == 0)
        out[b * 200 + n2] = acc + pr[b] + fc2_b[n2];
}

// ---------------------------------------------------------------------------
extern "C" void kernel_launch(void* const* d_in, const int* in_sizes, int n_in,
                              void* d_out, int out_size, void* d_ws, size_t ws_size,
                              hipStream_t stream) {
    const float* births    = (const float*)d_in[0];
    const float* lifetimes = (const float*)d_in[1];
    const int*   mask      = (const int*)d_in[2];
    const float* centers   = (const float*)d_in[3];
    const float* sharpness = (const float*)d_in[4];
    const float* w1        = (const float*)d_in[5];
    const float* w2        = (const float*)d_in[6];
    const float* l1_w      = (const float*)d_in[7];
    const float* l1_b      = (const float*)d_in[8];
    const float* bn1_g     = (const float*)d_in[9];
    const float* bn1_b     = (const float*)d_in[10];
    const float* l2_w      = (const float*)d_in[11];
    const float* l2_b      = (const float*)d_in[12];
    const float* fc1_w     = (const float*)d_in[13];
    const float* fc1_b     = (const float*)d_in[14];
    const float* bn2_g     = (const float*)d_in[15];
    const float* bn2_b     = (const float*)d_in[16];
    const float* fc2_w     = (const float*)d_in[17];
    const float* fc2_b     = (const float*)d_in[18];
    float* out = (float*)d_out;

    float* ws    = (float*)d_ws;
    float* z     = ws;                            // V*B*J   = 307200
    float* xT    = ws + 307200;                   // 800*B   = 102400
    float* y1n   = ws + 307200 + 102400;          // 500*B   = 64000

    slayer_kernel <<<V * B, 256, 0, stream>>>(births, lifetimes, mask, centers, sharpness, z);
    stage2_kernel <<<V, 1024, 0, stream>>>(z, w1, w2, l1_w, l1_b, bn1_g, bn1_b,
                                           l2_w, l2_b, xT);
    fc1_bn2_kernel<<<500, 256, 0, stream>>>(xT, fc1_w, fc1_b, bn2_g, bn2_b, y1n);
    fc2_kernel    <<<200, 256, 0, stream>>>(y1n, fc2_w, fc2_b, out);
}